// Round 2
// baseline (621.341 us; speedup 1.0000x reference)
//
#include <hip/hip_runtime.h>
#include <hip/hip_fp16.h>

// Problem constants
#define OUT_F 4096
#define IN_F  4096
#define M_TOTAL 8192          // 4 * 2048
#define TOTAL_W (OUT_F * IN_F)

typedef _Float16 f16x8  __attribute__((ext_vector_type(8)));
typedef float    f32x16 __attribute__((ext_vector_type(16)));

__device__ const float NF4_LUT_C[16] = {
    -1.0f, -0.6961928009986877f, -0.5250730514526367f, -0.39491748809814453f,
    -0.28444138169288635f, -0.18477343022823334f, -0.09105003625154495f, 0.0f,
    0.07958029955625534f, 0.16093020141124725f, 0.24611230194568634f,
    0.33791524171829224f, 0.44070982933044434f, 0.5626170039176941f,
    0.7229568362236023f, 1.0f};

// ---------------- Fused prep: dequant (blocks 0..8191) + cast (8192..24575) ----
#define DEQ_BLOCKS (TOTAL_W / 8 / 256)            // 8192
#define CAST_BLOCKS ((size_t)M_TOTAL * IN_F / 8 / 256)  // 16384

__global__ __launch_bounds__(256) void k_prep(const int* __restrict__ idx,
                                              const int* __restrict__ qs,
                                              _Float16* __restrict__ W,
                                              const float* __restrict__ x,
                                              _Float16* __restrict__ xh) {
    __shared__ float slut[16];
    if (threadIdx.x < 16) slut[threadIdx.x] = NF4_LUT_C[threadIdx.x];
    __syncthreads();
    if (blockIdx.x < DEQ_BLOCKS) {
        int t = blockIdx.x * 256 + threadIdx.x;          // 0 .. TOTAL_W/8-1
        const int4* ip = (const int4*)idx;
        int4 a = ip[2 * t];
        int4 b = ip[2 * t + 1];
        // exact reference order: (q/127)*0.05 in fp32, then vals*absmax, fp16 cast
        float absmax = ((float)qs[t >> 3] / 127.0f) * 0.05f;
        f16x8 o;
        o[0] = (_Float16)(slut[a.x] * absmax);
        o[1] = (_Float16)(slut[a.y] * absmax);
        o[2] = (_Float16)(slut[a.z] * absmax);
        o[3] = (_Float16)(slut[a.w] * absmax);
        o[4] = (_Float16)(slut[b.x] * absmax);
        o[5] = (_Float16)(slut[b.y] * absmax);
        o[6] = (_Float16)(slut[b.z] * absmax);
        o[7] = (_Float16)(slut[b.w] * absmax);
        *(f16x8*)(W + (size_t)t * 8) = o;
    } else {
        size_t t = (size_t)(blockIdx.x - DEQ_BLOCKS) * 256 + threadIdx.x;
        const float4* xp = (const float4*)x;
        float4 a = xp[2 * t];
        float4 b = xp[2 * t + 1];
        f16x8 o;
        o[0] = (_Float16)a.x; o[1] = (_Float16)a.y; o[2] = (_Float16)a.z; o[3] = (_Float16)a.w;
        o[4] = (_Float16)b.x; o[5] = (_Float16)b.y; o[6] = (_Float16)b.z; o[7] = (_Float16)b.w;
        *(f16x8*)(xh + t * 8) = o;
    }
}

// ---------------- GEMM: C[M][N] = A[M][K] * B[N][K]^T ----------------
// 256x256 tile, BK=32, 512 threads = 8 waves (2M x 4N), per-wave 128x64 via
// 4x2 frags of mfma_f32_32x32x16_f16, 2 k-steps per tile.
//
// Pipeline (1 barrier + counted vmcnt per K-tile):
//   4-buffer LDS ring (128 KiB), depth-3 global_load_lds prefetch.
//   Per tile t:  STAGE(t+3) | RD s0->setB | MFMA(setA: s1 of t-1) |
//                RD s1->setA | MFMA(setB: s0 of t) | lgkm(0) vmcnt(8) barrier
//   ds_reads overlap the previous k-step's MFMA cluster in-wave (ping-pong regs);
//   global loads have ~3 tiles of time to land; vmcnt never drains to 0 except
//   the 2-tile tail taper (8 -> 4 -> 0).
//   Hazards: lgkm(0) before the barrier => no DS read crosses a barrier;
//   STAGE(t+3) writes buf[(t+3)&3], whose readers (tile t-1) drained before the
//   barrier that precedes the stage issue.
//
// Swizzle (measured 0 conflicts in this family): 16B chunk (row r, pos c):
// physical c = logical ^ (r&3); staging pre-swizzles the GLOBAL k-offset so the
// LDS dest stays lane-linear (global_load_lds requirement); reads XOR with fr&3
// (invariant across 32-row sub-tiles).

__device__ __forceinline__ void async16(const _Float16* g, _Float16* l) {
    __builtin_amdgcn_global_load_lds(
        (const __attribute__((address_space(1))) void*)g,
        (__attribute__((address_space(3))) void*)l,
        16, 0, 0);
}

#define MFMA32(a, b, c) __builtin_amdgcn_mfma_f32_32x32x16_f16(a, b, c, 0, 0, 0)
#define BARRIER() asm volatile("s_barrier" ::: "memory")
#define VMCNT8()  asm volatile("s_waitcnt vmcnt(8)" ::: "memory")
#define VMCNT4()  asm volatile("s_waitcnt vmcnt(4)" ::: "memory")
#define VMCNT0()  asm volatile("s_waitcnt vmcnt(0)" ::: "memory")
#define LGKM0()   asm volatile("s_waitcnt lgkmcnt(0)" ::: "memory")

#define BK 32
#define TILE_E (256 * BK)     // 8192 elems = 16 KiB
#define NTILES (IN_F / BK)    // 128

__global__ __launch_bounds__(512, 2) void k_gemm(const _Float16* __restrict__ A,
                                                 const _Float16* __restrict__ B,
                                                 float* __restrict__ C) {
    const int K = IN_F, N = OUT_F;
    __shared__ __align__(1024) _Float16 sA[4][TILE_E];   // 64 KiB
    __shared__ __align__(1024) _Float16 sB[4][TILE_E];   // 64 KiB

    const int tid = threadIdx.x;
    // Raster: 32 groups of 16 blocks (4 bm x 4 bn) over 32x16 tile grid.
    const int bid = blockIdx.x;            // 0..511
    const int g   = bid >> 4;              // 0..31
    const int wv  = bid & 15;
    const int gy  = g >> 2;                // 0..7
    const int gx  = g & 3;                 // 0..3
    const int m0  = (gy * 4 + (wv >> 2)) * 256;
    const int n0  = (gx * 4 + (wv & 3)) * 256;

    const int lane = tid & 63;
    const int wave = tid >> 6;
    const int wm   = (wave >> 2) * 128;    // 0 or 128
    const int wn   = (wave & 3) * 64;      // 0,64,128,192

    // 32x32x16 fragment addressing: row/col = lane&31, k = (lane>>5)*8 + j
    const int fr  = lane & 31;
    const int h   = lane >> 5;
    const int swz = fr & 3;
    const int p0  = ((0 + h) ^ swz) * 8;   // k-step 0 phys elem offset in row
    const int p1  = ((2 + h) ^ swz) * 8;   // k-step 1

    // Staging: thread t covers phys chunks {t, 512+t}: row = j*128 + (t>>2),
    // pos = t&3, global kchunk = pos ^ (row&3) = (t&3)^((t>>2)&3) (j-invariant).
    const int rr = tid >> 2;                             // 0..127
    const int kc = ((tid & 3) ^ (rr & 3)) * 8;           // global k elem offset
    const _Float16* agp0 = A + (size_t)(m0 + rr) * K + kc;
    const _Float16* agp1 = A + (size_t)(m0 + 128 + rr) * K + kc;
    const _Float16* bgp0 = B + (size_t)(n0 + rr) * K + kc;
    const _Float16* bgp1 = B + (size_t)(n0 + 128 + rr) * K + kc;
    const int d0 = tid * 8;                              // LDS elem offsets
    const int d1 = 4096 + tid * 8;

#define STAGE(u) do {                                    \
        _Float16* la_ = &sA[(u) & 3][0];                 \
        _Float16* lb_ = &sB[(u) & 3][0];                 \
        const int ko_ = (u) * BK;                        \
        async16(agp0 + ko_, la_ + d0);                   \
        async16(agp1 + ko_, la_ + d1);                   \
        async16(bgp0 + ko_, lb_ + d0);                   \
        async16(bgp1 + ko_, lb_ + d1);                   \
    } while (0)

    // Fragment register sets (ping-pong)
    f16x8 A_a0, A_a1, A_a2, A_a3, A_b0, A_b1;
    f16x8 B_a0, B_a1, B_a2, B_a3, B_b0, B_b1;

#define RD(S, T, P) do {                                                  \
        const _Float16* a_ = &sA[(T) & 3][0];                             \
        const _Float16* b_ = &sB[(T) & 3][0];                             \
        S##a0 = *(const f16x8*)(a_ + (wm +  0 + fr) * BK + (P));          \
        S##a1 = *(const f16x8*)(a_ + (wm + 32 + fr) * BK + (P));          \
        S##a2 = *(const f16x8*)(a_ + (wm + 64 + fr) * BK + (P));          \
        S##a3 = *(const f16x8*)(a_ + (wm + 96 + fr) * BK + (P));          \
        S##b0 = *(const f16x8*)(b_ + (wn +  0 + fr) * BK + (P));          \
        S##b1 = *(const f16x8*)(b_ + (wn + 32 + fr) * BK + (P));          \
    } while (0)

    f32x16 acc00, acc01, acc10, acc11, acc20, acc21, acc30, acc31;
#pragma unroll
    for (int r = 0; r < 16; ++r) {
        acc00[r] = 0.f; acc01[r] = 0.f; acc10[r] = 0.f; acc11[r] = 0.f;
        acc20[r] = 0.f; acc21[r] = 0.f; acc30[r] = 0.f; acc31[r] = 0.f;
    }

#define MM(S) do {                                                        \
        __builtin_amdgcn_s_setprio(1);                                    \
        acc00 = MFMA32(S##a0, S##b0, acc00);                              \
        acc01 = MFMA32(S##a0, S##b1, acc01);                              \
        acc10 = MFMA32(S##a1, S##b0, acc10);                              \
        acc11 = MFMA32(S##a1, S##b1, acc11);                              \
        acc20 = MFMA32(S##a2, S##b0, acc20);                              \
        acc21 = MFMA32(S##a2, S##b1, acc21);                              \
        acc30 = MFMA32(S##a3, S##b0, acc30);                              \
        acc31 = MFMA32(S##a3, S##b1, acc31);                              \
        __builtin_amdgcn_s_setprio(0);                                    \
    } while (0)

    // ---- prologue: depth-3 prefetch ----
    STAGE(0); STAGE(1); STAGE(2);
    VMCNT8();            // tile 0 landed; 1,2 in flight
    BARRIER();

    // ---- t = 0 (peeled: no previous-tile MFMA) ----
    STAGE(3);
    RD(B_, 0, p0);
    RD(A_, 0, p1);
    MM(B_);              // s0 of tile 0
    LGKM0();
    VMCNT8();            // tile 1 landed
    BARRIER();

    // ---- steady state ----
    for (int t = 1; t < NTILES; ++t) {
        if (t + 3 < NTILES) STAGE(t + 3);
        RD(B_, t, p0);   // s0 of t  (overlaps MFMA below)
        MM(A_);          // s1 of t-1
        RD(A_, t, p1);   // s1 of t  (overlaps MFMA below)
        MM(B_);          // s0 of t
        LGKM0();         // no DS read crosses the barrier
        if (t <= NTILES - 4)      { VMCNT8(); }   // t+1 landed, t+2/t+3 in flight
        else if (t == NTILES - 3) { VMCNT4(); }   // t+1 landed
        else if (t == NTILES - 2) { VMCNT0(); }   // last tile landed
        if (t < NTILES - 1) BARRIER();
    }
    MM(A_);              // s1 of tile NTILES-1

    // Epilogue: 32x32 C/D layout col=lane&31, row=(r&3)+8*(r>>2)+4*(lane>>5)
#define STORE(ACC, MI, NI) do {                                           \
        _Pragma("unroll")                                                 \
        for (int r = 0; r < 16; ++r) {                                    \
            int row_ = m0 + wm + (MI)*32 + (r & 3) + 8 * (r >> 2) + 4 * h;\
            C[(size_t)row_ * N + (n0 + wn + (NI)*32 + fr)] = ACC[r];      \
        }                                                                 \
    } while (0)

    STORE(acc00, 0, 0); STORE(acc01, 0, 1);
    STORE(acc10, 1, 0); STORE(acc11, 1, 1);
    STORE(acc20, 2, 0); STORE(acc21, 2, 1);
    STORE(acc30, 3, 0); STORE(acc31, 3, 1);
}

extern "C" void kernel_launch(void* const* d_in, const int* in_sizes, int n_in,
                              void* d_out, int out_size, void* d_ws, size_t ws_size,
                              hipStream_t stream) {
    const float* x       = (const float*)d_in[0];
    const int*   indices = (const int*)d_in[1];
    const int*   qscales = (const int*)d_in[2];
    float*       out     = (float*)d_out;

    _Float16* W  = (_Float16*)d_ws;                                   // 32 MiB
    _Float16* Xh = (_Float16*)((char*)d_ws + (size_t)TOTAL_W * 2);    // 64 MiB

    k_prep<<<DEQ_BLOCKS + (int)CAST_BLOCKS, 256, 0, stream>>>(indices, qscales, W, x, Xh);
    k_gemm<<<512, 512, 0, stream>>>(W == nullptr ? nullptr : Xh, W, out);
}

// Round 3
// 537.207 us; speedup vs baseline: 1.1566x; 1.1566x over previous
//
#include <hip/hip_runtime.h>
#include <hip/hip_fp16.h>

// Problem constants
#define OUT_F 4096
#define IN_F  4096
#define M_TOTAL 8192          // 4 * 2048
#define TOTAL_W (OUT_F * IN_F)

typedef _Float16 f16x8  __attribute__((ext_vector_type(8)));
typedef float    f32x16 __attribute__((ext_vector_type(16)));

__device__ const float NF4_LUT_C[16] = {
    -1.0f, -0.6961928009986877f, -0.5250730514526367f, -0.39491748809814453f,
    -0.28444138169288635f, -0.18477343022823334f, -0.09105003625154495f, 0.0f,
    0.07958029955625534f, 0.16093020141124725f, 0.24611230194568634f,
    0.33791524171829224f, 0.44070982933044434f, 0.5626170039176941f,
    0.7229568362236023f, 1.0f};

// ---------------- Fused prep: dequant (blocks 0..8191) + cast (8192..24575) ----
#define DEQ_BLOCKS (TOTAL_W / 8 / 256)                  // 8192
#define CAST_BLOCKS ((size_t)M_TOTAL * IN_F / 8 / 256)  // 16384

__global__ __launch_bounds__(256) void k_prep(const int* __restrict__ idx,
                                              const int* __restrict__ qs,
                                              _Float16* __restrict__ W,
                                              const float* __restrict__ x,
                                              _Float16* __restrict__ xh) {
    // 32 replicated LUT copies: lane pair (l>>1) owns copy c; banks (c*16+i)%32
    // put even copies in banks 0-15, odd in 16-31 -> ~2-way random (free) vs
    // 4-way with a single 16-entry copy.
    __shared__ float slut[32][16];
    for (int i = threadIdx.x; i < 512; i += 256) slut[i >> 4][i & 15] = NF4_LUT_C[i & 15];
    __syncthreads();
    if (blockIdx.x < DEQ_BLOCKS) {
        const float* myl = slut[(threadIdx.x & 63) >> 1];
        int t = blockIdx.x * 256 + threadIdx.x;          // 0 .. TOTAL_W/8-1
        const int4* ip = (const int4*)idx;
        int4 a = ip[2 * t];
        int4 b = ip[2 * t + 1];
        // exact reference order: (q/127)*0.05 in fp32, then vals*absmax, fp16 cast
        float absmax = ((float)qs[t >> 3] / 127.0f) * 0.05f;
        f16x8 o;
        o[0] = (_Float16)(myl[a.x] * absmax);
        o[1] = (_Float16)(myl[a.y] * absmax);
        o[2] = (_Float16)(myl[a.z] * absmax);
        o[3] = (_Float16)(myl[a.w] * absmax);
        o[4] = (_Float16)(myl[b.x] * absmax);
        o[5] = (_Float16)(myl[b.y] * absmax);
        o[6] = (_Float16)(myl[b.z] * absmax);
        o[7] = (_Float16)(myl[b.w] * absmax);
        *(f16x8*)(W + (size_t)t * 8) = o;
    } else {
        size_t t = (size_t)(blockIdx.x - DEQ_BLOCKS) * 256 + threadIdx.x;
        const float4* xp = (const float4*)x;
        float4 a = xp[2 * t];
        float4 b = xp[2 * t + 1];
        f16x8 o;
        o[0] = (_Float16)a.x; o[1] = (_Float16)a.y; o[2] = (_Float16)a.z; o[3] = (_Float16)a.w;
        o[4] = (_Float16)b.x; o[5] = (_Float16)b.y; o[6] = (_Float16)b.z; o[7] = (_Float16)b.w;
        *(f16x8*)(xh + t * 8) = o;
    }
}

// ---------------- GEMM: C[M][N] = A[M][K] * B[N][K]^T ----------------
// 256x256 tile, BK=64, 512 threads = 8 waves (2M x 4N), per-wave 128x64 via
// 4x2 frags of mfma_f32_32x32x16_f16 (4 k-steps per tile).
//
// One-phase-ahead fragment pipeline, 4 phases/tile, 2-buffer ring (128 KiB):
//   ph1: rd B1(t)[4]          | bar lgkm(4) | MFMA {Alo x B0}  | bar
//   ph2: vmcnt(0); rd Ahi(t)[8]| bar lgkm(8) | MFMA {Alo x B1}  | bar
//        (vmcnt(0) queue holds ONLY tile-t+1 stages issued ~6 phases ago ->
//         free; + the barrier makes t+1 all-waves-visible for ph3 prefetch)
//   ph3: stageB(t+2); rd Alo(t+1)[8] | bar lgkm(8) | MFMA {Ahi x B1} | bar
//   ph4: stageA(t+2) | MFMA {Ahi x B0} | rd B0(t+1)[4] tail | bar
// Every MFMA cluster's operands were ds_read-issued >= 1 phase earlier; the
// counted lgkm retires exactly them (in-order DS retirement). Buffer-reuse
// safety: stageB(t+2)->sB[cur] after ph2's bar (all waves' B(t) reads retired
// at their ph1-lgkm(4)/ph2-lgkm(8)); stageA(t+2)->sA[cur] after ph3's bar
// (Ahi(t) retired at ph3-lgkm(8), Alo(t) at ph1-lgkm(4)).
//
// Swizzle (round-1 proven, 0 conflicts): 16B chunk (row r, pos c) at physical
// r*8 + (c ^ (r&7)); staging pre-swizzles the GLOBAL k-offset so the LDS dest
// stays lane-linear; reads XOR with fr&7 (8 consecutive lanes hit all 8
// 16B-slots -> conflict-free for any 8-lane service grouping).

__device__ __forceinline__ void async16(const _Float16* g, _Float16* l) {
    __builtin_amdgcn_global_load_lds(
        (const __attribute__((address_space(1))) void*)g,
        (__attribute__((address_space(3))) void*)l,
        16, 0, 0);
}

#define MFMA32(a, b, c) __builtin_amdgcn_mfma_f32_32x32x16_f16(a, b, c, 0, 0, 0)
#define BAR()    __builtin_amdgcn_s_barrier()
#define VMCNT(n) asm volatile("s_waitcnt vmcnt(" #n ")" ::: "memory")
#define LGKM(n)  asm volatile("s_waitcnt lgkmcnt(" #n ")" ::: "memory")
#define PRIO(n)  __builtin_amdgcn_s_setprio(n)

#define BK 64
#define TILE_E (256 * BK)     // 16384 elems = 32 KiB
#define NT (IN_F / BK)        // 64

__global__ __launch_bounds__(512, 2) void k_gemm(const _Float16* __restrict__ A,
                                                 const _Float16* __restrict__ B,
                                                 float* __restrict__ C) {
    const int K = IN_F, N = OUT_F;
    __shared__ __align__(1024) _Float16 sAm[2 * TILE_E];   // 64 KiB
    __shared__ __align__(1024) _Float16 sBm[2 * TILE_E];   // 64 KiB
    _Float16* sA0 = &sAm[0];
    _Float16* sB0 = &sBm[0];

    const int tid = threadIdx.x;
    // Raster: 32 groups of 16 blocks (4 bm x 4 bn) over 32x16 tile grid.
    const int bid = blockIdx.x;            // 0..511
    const int g   = bid >> 4;              // 0..31
    const int wv  = bid & 15;
    const int gy  = g >> 2;                // 0..7
    const int gx  = g & 3;                 // 0..3
    const int m0  = (gy * 4 + (wv >> 2)) * 256;
    const int n0  = (gx * 4 + (wv & 3)) * 256;

    const int lane = tid & 63;
    const int wave = tid >> 6;
    const int wm   = (wave >> 2) * 128;    // 0 or 128
    const int wn   = (wave & 3) * 64;      // 0,64,128,192

    // 32x32x16 fragment addressing: row/col = lane&31, k = (lane>>5)*8 + j.
    // k-step s reads logical chunk 2s+h of the 8 chunks per 64-elem row.
    const int fr  = lane & 31;
    const int h   = lane >> 5;
    const int sw8 = fr & 7;
    const int aOff = (wm + fr) * BK;       // elem offset of A frag row base
    const int bOff = (wn + fr) * BK;
    const int ps0 = ((0 + h) ^ sw8) * 8;
    const int ps1 = ((2 + h) ^ sw8) * 8;
    const int ps2 = ((4 + h) ^ sw8) * 8;
    const int ps3 = ((6 + h) ^ sw8) * 8;

    // Staging: thread t, pass j fills phys chunk j*512+t: row = j*64 + (t>>3),
    // pos = t&7, global kchunk = pos ^ (row&7) = (t&7)^((t>>3)&7) (j-invariant).
    const int rr  = tid >> 3;                              // 0..63
    const int kc  = ((tid & 7) ^ (rr & 7)) * 8;            // global k elem offset
    const _Float16* agp = A + (size_t)(m0 + rr) * K + kc;
    const _Float16* bgp = B + (size_t)(n0 + rr) * K + kc;
    const int dOff = tid * 8;                              // LDS dest elem offset

#define STAGE_A(T) do {                                                       \
        _Float16* d_ = sA0 + ((T) & 1) * TILE_E + dOff;                       \
        const size_t ko_ = (size_t)(T) * BK;                                  \
        async16(agp + ko_,                       d_);                         \
        async16(agp + ko_ + (size_t) 64 * K,     d_ + 4096);                  \
        async16(agp + ko_ + (size_t)128 * K,     d_ + 8192);                  \
        async16(agp + ko_ + (size_t)192 * K,     d_ + 12288);                 \
    } while (0)
#define STAGE_B(T) do {                                                       \
        _Float16* d_ = sB0 + ((T) & 1) * TILE_E + dOff;                       \
        const size_t ko_ = (size_t)(T) * BK;                                  \
        async16(bgp + ko_,                       d_);                         \
        async16(bgp + ko_ + (size_t) 64 * K,     d_ + 4096);                  \
        async16(bgp + ko_ + (size_t)128 * K,     d_ + 8192);                  \
        async16(bgp + ko_ + (size_t)192 * K,     d_ + 12288);                 \
    } while (0)

    // Fragment registers: A frags (rows wm + mf*32), B frags (cols wn + nf*32)
    f16x8 aLo0[4], aLo1[4], aHi0[4], aHi1[4], b0f[4], b1f[4];

#define RD_A(dst, T, mf) do {                                                 \
        const _Float16* p_ = sA0 + ((T) & 1) * TILE_E + aOff + (mf) * 2048;   \
        dst[0] = *(const f16x8*)(p_ + ps0);                                   \
        dst[1] = *(const f16x8*)(p_ + ps1);                                   \
        dst[2] = *(const f16x8*)(p_ + ps2);                                   \
        dst[3] = *(const f16x8*)(p_ + ps3);                                   \
    } while (0)
#define RD_B(dst, T, nf) do {                                                 \
        const _Float16* p_ = sB0 + ((T) & 1) * TILE_E + bOff + (nf) * 2048;   \
        dst[0] = *(const f16x8*)(p_ + ps0);                                   \
        dst[1] = *(const f16x8*)(p_ + ps1);                                   \
        dst[2] = *(const f16x8*)(p_ + ps2);                                   \
        dst[3] = *(const f16x8*)(p_ + ps3);                                   \
    } while (0)

    f32x16 acc00, acc01, acc10, acc11, acc20, acc21, acc30, acc31;
#pragma unroll
    for (int r = 0; r < 16; ++r) {
        acc00[r] = 0.f; acc01[r] = 0.f; acc10[r] = 0.f; acc11[r] = 0.f;
        acc20[r] = 0.f; acc21[r] = 0.f; acc30[r] = 0.f; acc31[r] = 0.f;
    }

    // Two independent acc chains interleaved per cluster (8 MFMA).
#define MM2(af0, af1, bfv, accA, accB) do {                                   \
        PRIO(1);                                                              \
        accA = MFMA32(af0[0], bfv[0], accA);                                  \
        accB = MFMA32(af1[0], bfv[0], accB);                                  \
        accA = MFMA32(af0[1], bfv[1], accA);                                  \
        accB = MFMA32(af1[1], bfv[1], accB);                                  \
        accA = MFMA32(af0[2], bfv[2], accA);                                  \
        accB = MFMA32(af1[2], bfv[2], accB);                                  \
        accA = MFMA32(af0[3], bfv[3], accA);                                  \
        accB = MFMA32(af1[3], bfv[3], accB);                                  \
        PRIO(0);                                                              \
    } while (0)

    // ---- prologue: stage tiles 0,1; confirm tile 0; pre-read ph1 operands ----
    STAGE_B(0); STAGE_A(0); STAGE_B(1); STAGE_A(1);
    VMCNT(8);            // tile 0 landed; tile 1 in flight
    BAR();
    RD_A(aLo0, 0, 0); RD_A(aLo1, 0, 1);
    RD_B(b0f, 0, 0);

#pragma unroll 2
    for (int t = 0; t < NT; ++t) {
        // ---------- phase 1 ----------
        RD_B(b1f, t, 1);
        BAR();
        LGKM(4);                         // Alo(t), B0(t) retired; B1 in flight
        MM2(aLo0, aLo1, b0f, acc00, acc10);
        BAR();
        // ---------- phase 2 ----------
        VMCNT(0);                        // queue = tile t+1 stages (old) -> ~free
        RD_A(aHi0, t, 2); RD_A(aHi1, t, 3);
        BAR();                           // all waves confirmed t+1; B(t) reads retired
        LGKM(8);                         // B1 retired; Ahi in flight
        MM2(aLo0, aLo1, b1f, acc01, acc11);
        BAR();
        // ---------- phase 3 ----------
        if (t + 2 < NT) STAGE_B(t + 2);  // sB[cur] dead (all B(t) reads retired)
        if (t + 1 < NT) { RD_A(aLo0, t + 1, 0); RD_A(aLo1, t + 1, 1); }
        BAR();
        LGKM(8);                         // Ahi retired; Alo(t+1) in flight
                                         // (tail tile: compiler auto-wait covers)
        MM2(aHi0, aHi1, b1f, acc21, acc31);
        BAR();                           // all waves' Ahi retired -> A stage safe
        // ---------- phase 4 ----------
        if (t + 2 < NT) STAGE_A(t + 2);
        MM2(aHi0, aHi1, b0f, acc20, acc30);
        if (t + 1 < NT) RD_B(b0f, t + 1, 0);   // tail read into dead regs
        BAR();
    }

    // Epilogue: 32x32 C/D layout col=lane&31, row=(r&3)+8*(r>>2)+4*(lane>>5)
#define STORE(ACC, MI, NI) do {                                               \
        _Pragma("unroll")                                                     \
        for (int r = 0; r < 16; ++r) {                                        \
            int row_ = m0 + wm + (MI)*32 + (r & 3) + 8 * (r >> 2) + 4 * h;    \
            C[(size_t)row_ * N + (n0 + wn + (NI)*32 + fr)] = ACC[r];          \
        }                                                                     \
    } while (0)

    STORE(acc00, 0, 0); STORE(acc01, 0, 1);
    STORE(acc10, 1, 0); STORE(acc11, 1, 1);
    STORE(acc20, 2, 0); STORE(acc21, 2, 1);
    STORE(acc30, 3, 0); STORE(acc31, 3, 1);
}

extern "C" void kernel_launch(void* const* d_in, const int* in_sizes, int n_in,
                              void* d_out, int out_size, void* d_ws, size_t ws_size,
                              hipStream_t stream) {
    const float* x       = (const float*)d_in[0];
    const int*   indices = (const int*)d_in[1];
    const int*   qscales = (const int*)d_in[2];
    float*       out     = (float*)d_out;

    _Float16* W  = (_Float16*)d_ws;                                   // 32 MiB
    _Float16* Xh = (_Float16*)((char*)d_ws + (size_t)TOTAL_W * 2);    // 64 MiB

    k_prep<<<DEQ_BLOCKS + (int)CAST_BLOCKS, 256, 0, stream>>>(indices, qscales, W, x, Xh);
    k_gemm<<<512, 512, 0, stream>>>(Xh, W, out);
}

// Round 4
// 530.898 us; speedup vs baseline: 1.1704x; 1.0119x over previous
//
#include <hip/hip_runtime.h>
#include <hip/hip_fp16.h>

// Problem constants
#define OUT_F 4096
#define IN_F  4096
#define M_TOTAL 8192          // 4 * 2048
#define TOTAL_W (OUT_F * IN_F)

typedef _Float16 f16x8 __attribute__((ext_vector_type(8)));
typedef float    f32x4 __attribute__((ext_vector_type(4)));

__device__ const float NF4_LUT_C[16] = {
    -1.0f, -0.6961928009986877f, -0.5250730514526367f, -0.39491748809814453f,
    -0.28444138169288635f, -0.18477343022823334f, -0.09105003625154495f, 0.0f,
    0.07958029955625534f, 0.16093020141124725f, 0.24611230194568634f,
    0.33791524171829224f, 0.44070982933044434f, 0.5626170039176941f,
    0.7229568362236023f, 1.0f};

// ---------------- Fused prep: dequant (blocks 0..8191) + cast (8192..24575) ----
#define DEQ_BLOCKS (TOTAL_W / 8 / 256)                  // 8192
#define CAST_BLOCKS ((size_t)M_TOTAL * IN_F / 8 / 256)  // 16384

__global__ __launch_bounds__(256) void k_prep(const int* __restrict__ idx,
                                              const int* __restrict__ qs,
                                              _Float16* __restrict__ W,
                                              const float* __restrict__ x,
                                              _Float16* __restrict__ xh) {
    // 32 replicated LUT copies, lane pair (l>>1) owns copy c -> ~2-way random
    __shared__ float slut[32][16];
    for (int i = threadIdx.x; i < 512; i += 256) slut[i >> 4][i & 15] = NF4_LUT_C[i & 15];
    __syncthreads();
    if (blockIdx.x < DEQ_BLOCKS) {
        const float* myl = slut[(threadIdx.x & 63) >> 1];
        int t = blockIdx.x * 256 + threadIdx.x;          // 0 .. TOTAL_W/8-1
        const int4* ip = (const int4*)idx;
        int4 a = ip[2 * t];
        int4 b = ip[2 * t + 1];
        // exact reference order: (q/127)*0.05 in fp32, then vals*absmax, fp16 cast
        float absmax = ((float)qs[t >> 3] / 127.0f) * 0.05f;
        f16x8 o;
        o[0] = (_Float16)(myl[a.x] * absmax);
        o[1] = (_Float16)(myl[a.y] * absmax);
        o[2] = (_Float16)(myl[a.z] * absmax);
        o[3] = (_Float16)(myl[a.w] * absmax);
        o[4] = (_Float16)(myl[b.x] * absmax);
        o[5] = (_Float16)(myl[b.y] * absmax);
        o[6] = (_Float16)(myl[b.z] * absmax);
        o[7] = (_Float16)(myl[b.w] * absmax);
        *(f16x8*)(W + (size_t)t * 8) = o;
    } else {
        size_t t = (size_t)(blockIdx.x - DEQ_BLOCKS) * 256 + threadIdx.x;
        const float4* xp = (const float4*)x;
        float4 a = xp[2 * t];
        float4 b = xp[2 * t + 1];
        f16x8 o;
        o[0] = (_Float16)a.x; o[1] = (_Float16)a.y; o[2] = (_Float16)a.z; o[3] = (_Float16)a.w;
        o[4] = (_Float16)b.x; o[5] = (_Float16)b.y; o[6] = (_Float16)b.z; o[7] = (_Float16)b.w;
        *(f16x8*)(xh + t * 8) = o;
    }
}

// ---------------- GEMM: C[M][N] = A[M][K] * B[N][K]^T ----------------
// 256x256 tile, BK=64, 512 threads = 8 waves (2M x 4N), per-wave 128x64 via
// 8x4 frags of mfma_f32_16x16x32_f16 (2 k-steps per BK). Geometry, swizzle,
// staging and epilogue are byte-identical to the round-1 kernel (measured:
// 0 LDS bank conflicts, passed). Only the SCHEDULE changes: one-phase-ahead
// ds_reads with counted lgkm, 2 barriers/tile instead of 8.
//
// Steady-state tile t (clusters C1=A03xB01, C2=A03xB23, C3=A47xB01, C4=A47xB23):
//  ph1: issue rdA47(t)[8]; lgkm(8) [retires A03(t),B(t)]; C1
//  ph2: vmcnt(0) [queue = STAGE(t+1), issued 1 tile ago -> ~free]; BAR
//       [all waves' stages of t+1 now visible]; C2
//  ph3: issue rdA03(t+1)[8] (other buffer); lgkm(8) [retires A47(t)]; C3;
//       BAR [every wave retired ALL tile-t reads -> buf(t&1) dead]
//  ph4: STAGE(t+2)->buf(t&1) [safe per ph3 BAR]; issue rdB01(t+1)[4]; C4
//       (C4 uses bf23(t), untouched); issue rdB23(t+1)[4]
//  Next ph1's lgkm(8) retires A03(t+1)+B01+B23 exactly (in-order DS retire).
// No register ping-pong: each set's last MFMA use precedes its overwrite phase.
//
// Swizzle (proven 0-conflict): 16B chunk (row r, pos c) at physical r*8+(c^(r&7));
// staging pre-swizzles the GLOBAL k-offset, LDS dest stays lane-linear; reads
// use pos=((ks*4+fk)^(fr&7))*8 -> each 8-lane group covers all 8 slots.

__device__ __forceinline__ void async16(const _Float16* g, _Float16* l) {
    __builtin_amdgcn_global_load_lds(
        (const __attribute__((address_space(1))) void*)g,
        (__attribute__((address_space(3))) void*)l,
        16, 0, 0);
}

#define MFMA16(a, b, c) __builtin_amdgcn_mfma_f32_16x16x32_f16(a, b, c, 0, 0, 0)
#define BAR()    __builtin_amdgcn_s_barrier()
#define VMCNT(n) asm volatile("s_waitcnt vmcnt(" #n ")" ::: "memory")
#define LGKM(n)  asm volatile("s_waitcnt lgkmcnt(" #n ")" ::: "memory")
#define PRIO(n)  __builtin_amdgcn_s_setprio(n)

#define TILE_E (256 * 64)     // 16384 elems = 32 KiB
#define NT (IN_F / 64)        // 64

__global__ __launch_bounds__(512, 2) void k_gemm(const _Float16* __restrict__ A,
                                                 const _Float16* __restrict__ B,
                                                 float* __restrict__ C) {
    const int K = IN_F, N = OUT_F;
    __shared__ __align__(1024) _Float16 sAm[2 * TILE_E];   // 64 KiB
    __shared__ __align__(1024) _Float16 sBm[2 * TILE_E];   // 64 KiB
    _Float16* sA0 = &sAm[0];
    _Float16* sB0 = &sBm[0];

    const int tid = threadIdx.x;
    // Raster: 32 groups of 16 blocks (4 bm x 4 bn) over 32x16 tile grid.
    const int bid = blockIdx.x;            // 0..511
    const int g   = bid >> 4;              // 0..31
    const int wv  = bid & 15;
    const int gy  = g >> 2;                // 0..7
    const int gx  = g & 3;                 // 0..3
    const int m0  = (gy * 4 + (wv >> 2)) * 256;
    const int n0  = (gx * 4 + (wv & 3)) * 256;

    const int lane = tid & 63;
    const int wave = tid >> 6;
    const int wm   = (wave >> 2) * 128;    // 0 or 128
    const int wn   = (wave & 3) * 64;      // 0,64,128,192

    // 16x16x32 fragment addressing: row/col = lane&15, k-chunk = lane>>4
    const int fr   = lane & 15;
    const int fk   = lane >> 4;
    const int sw   = fr & 7;
    const int aRow = (wm + fr) * 64;       // element offset of frag row base
    const int bRow = (wn + fr) * 64;
    const int p0   = ((0 * 4 + fk) ^ sw) * 8;   // kstep 0 phys offset (elems)
    const int p1   = ((1 * 4 + fk) ^ sw) * 8;   // kstep 1

    // Staging: thread t, pass j fills phys chunk j*512+t: row = j*64 + (t>>3),
    // pos = t&7, global kchunk = pos ^ (row&7) = (t&7)^((t>>3)&7) (j-invariant).
    const int rr  = tid >> 3;                              // 0..63
    const int kc  = ((tid & 7) ^ (rr & 7)) * 8;            // global k elem offset
    const _Float16* agp = A + (size_t)(m0 + rr) * K + kc;
    const _Float16* bgp = B + (size_t)(n0 + rr) * K + kc;
    const int dOff = tid * 8;                              // LDS dest elem offset

#define STAGE(T) do {                                                         \
        _Float16* da_ = sA0 + ((T) & 1) * TILE_E + dOff;                      \
        _Float16* db_ = sB0 + ((T) & 1) * TILE_E + dOff;                      \
        const size_t ko_ = (size_t)(T) * 64;                                  \
        async16(agp + ko_,                   da_);                            \
        async16(agp + ko_ + (size_t)64 * K,  da_ + 4096);                     \
        async16(agp + ko_ + (size_t)128 * K, da_ + 8192);                     \
        async16(agp + ko_ + (size_t)192 * K, da_ + 12288);                    \
        async16(bgp + ko_,                   db_);                            \
        async16(bgp + ko_ + (size_t)64 * K,  db_ + 4096);                     \
        async16(bgp + ko_ + (size_t)128 * K, db_ + 8192);                     \
        async16(bgp + ko_ + (size_t)192 * K, db_ + 12288);                    \
    } while (0)

    // Fragment registers
    f16x8 a03[4][2], a47[4][2], bf[4][2];

#define RD_A03(T) do {                                                        \
        const _Float16* p_ = sA0 + ((T) & 1) * TILE_E + aRow;                 \
        _Pragma("unroll")                                                     \
        for (int mi = 0; mi < 4; ++mi) {                                      \
            a03[mi][0] = *(const f16x8*)(p_ + mi * 1024 + p0);                \
            a03[mi][1] = *(const f16x8*)(p_ + mi * 1024 + p1);                \
        }                                                                     \
    } while (0)
#define RD_A47(T) do {                                                        \
        const _Float16* p_ = sA0 + ((T) & 1) * TILE_E + aRow + 4096;          \
        _Pragma("unroll")                                                     \
        for (int mi = 0; mi < 4; ++mi) {                                      \
            a47[mi][0] = *(const f16x8*)(p_ + mi * 1024 + p0);                \
            a47[mi][1] = *(const f16x8*)(p_ + mi * 1024 + p1);                \
        }                                                                     \
    } while (0)
#define RD_B01(T) do {                                                        \
        const _Float16* p_ = sB0 + ((T) & 1) * TILE_E + bRow;                 \
        _Pragma("unroll")                                                     \
        for (int ni = 0; ni < 2; ++ni) {                                      \
            bf[ni][0] = *(const f16x8*)(p_ + ni * 1024 + p0);                 \
            bf[ni][1] = *(const f16x8*)(p_ + ni * 1024 + p1);                 \
        }                                                                     \
    } while (0)
#define RD_B23(T) do {                                                        \
        const _Float16* p_ = sB0 + ((T) & 1) * TILE_E + bRow;                 \
        _Pragma("unroll")                                                     \
        for (int ni = 2; ni < 4; ++ni) {                                      \
            bf[ni][0] = *(const f16x8*)(p_ + ni * 1024 + p0);                 \
            bf[ni][1] = *(const f16x8*)(p_ + ni * 1024 + p1);                 \
        }                                                                     \
    } while (0)

    f32x4 acc[8][4];
#pragma unroll
    for (int mi = 0; mi < 8; ++mi)
#pragma unroll
        for (int ni = 0; ni < 4; ++ni)
#pragma unroll
            for (int r = 0; r < 4; ++r) acc[mi][ni][r] = 0.f;

    // 16-MFMA cluster: A-set x 2 B-columns, 8 independent acc chains
#define MMC(ASET, AB, NB) do {                                                \
        PRIO(1);                                                              \
        _Pragma("unroll")                                                     \
        for (int mi = 0; mi < 4; ++mi) {                                      \
            acc[AB + mi][NB + 0] =                                            \
                MFMA16(ASET[mi][0], bf[NB + 0][0], acc[AB + mi][NB + 0]);     \
            acc[AB + mi][NB + 1] =                                            \
                MFMA16(ASET[mi][0], bf[NB + 1][0], acc[AB + mi][NB + 1]);     \
        }                                                                     \
        _Pragma("unroll")                                                     \
        for (int mi = 0; mi < 4; ++mi) {                                      \
            acc[AB + mi][NB + 0] =                                            \
                MFMA16(ASET[mi][1], bf[NB + 0][1], acc[AB + mi][NB + 0]);     \
            acc[AB + mi][NB + 1] =                                            \
                MFMA16(ASET[mi][1], bf[NB + 1][1], acc[AB + mi][NB + 1]);     \
        }                                                                     \
        PRIO(0);                                                              \
    } while (0)

    // ---- prologue ----
    STAGE(0); STAGE(1);
    VMCNT(8);            // tile 0 landed; tile 1 in flight
    BAR();
    RD_A03(0); RD_B01(0); RD_B23(0);   // 16 ds_reads outstanding

    for (int t = 0; t < NT; ++t) {
        // ---------- phase 1 ----------
        RD_A47(t);                       // +8 -> 24 outstanding
        LGKM(8);                         // A03(t), B(t) retired; A47 in flight
        MMC(a03, 0, 0);                  // C1 = A03 x B01
        // ---------- phase 2 ----------
        VMCNT(0);                        // STAGE(t+1) landed (issued 1 tile ago)
        BAR();                           // all waves' t+1 stages visible
        MMC(a03, 0, 2);                  // C2 = A03 x B23
        // ---------- phase 3 ----------
        if (t + 1 < NT) {
            RD_A03(t + 1);               // other buffer; visible per ph2 BAR
            LGKM(8);                     // retires A47(t); A03(t+1) in flight
        } else {
            LGKM(0);                     // tail: just retire A47
        }
        MMC(a47, 4, 0);                  // C3 = A47 x B01
        BAR();                           // every wave retired ALL tile-t reads
        // ---------- phase 4 ----------
        if (t + 2 < NT) STAGE(t + 2);    // -> buf(t&1), dead per ph3 BAR
        if (t + 1 < NT) RD_B01(t + 1);   // bf01 dead (C3 done); C4 uses bf23
        MMC(a47, 4, 2);                  // C4 = A47 x B23
        if (t + 1 < NT) RD_B23(t + 1);   // bf23 dead after C4
    }

    // Epilogue: 16x16x32 C/D layout col=lane&15, row=(lane>>4)*4+reg
    const int crow0 = m0 + wm + fk * 4;
    const int ccol0 = n0 + wn + fr;
#pragma unroll
    for (int mi = 0; mi < 8; ++mi)
#pragma unroll
        for (int ni = 0; ni < 4; ++ni)
#pragma unroll
            for (int r = 0; r < 4; ++r)
                C[(size_t)(crow0 + mi * 16 + r) * N + ccol0 + ni * 16] = acc[mi][ni][r];
}

extern "C" void kernel_launch(void* const* d_in, const int* in_sizes, int n_in,
                              void* d_out, int out_size, void* d_ws, size_t ws_size,
                              hipStream_t stream) {
    const float* x       = (const float*)d_in[0];
    const int*   indices = (const int*)d_in[1];
    const int*   qscales = (const int*)d_in[2];
    float*       out     = (float*)d_out;

    _Float16* W  = (_Float16*)d_ws;                                   // 32 MiB
    _Float16* Xh = (_Float16*)((char*)d_ws + (size_t)TOTAL_W * 2);    // 64 MiB

    k_prep<<<DEQ_BLOCKS + (int)CAST_BLOCKS, 256, 0, stream>>>(indices, qscales, W, x, Xh);
    k_gemm<<<512, 512, 0, stream>>>(Xh, W, out);
}